// Round 5
// baseline (291.309 us; speedup 1.0000x reference)
//
#include <hip/hip_runtime.h>

// Problem constants (fixed by the reference file)
#define BATCH   8
#define C_OUT_N 96
#define NK      11
#define C_IN_N  1056      // C_OUT_N * NK
#define GRP     4
#define HOUT    56
#define WOUT    56
#define HIN     60
#define WIN     60
#define EP      2

// Column-major LDS tile: tile[col*TSTR + row + RPAD]
// rows padded to absorb vertical OOB: row in [-27, 78] -> 106 entries
#define RPAD    27
#define TSTR    107               // odd stride: lane-stride-107 reads are conflict-free
#define TILE_DW (WIN * TSTR)      // 60*107 = 6420 dwords = 25680 B
#define NELEM   (HIN * WIN)       // 3600

typedef float fvec4 __attribute__((ext_vector_type(4)));   // native vec for nontemporal

// One block per (b, co); 512 threads = 8 waves; wave wv owns output rows wv*7..wv*7+6.
__global__ __launch_bounds__(512, 6) void addshift_kernel(
    const float* __restrict__ x,
    const float* __restrict__ w1,
    const float* __restrict__ w2,
    const float* __restrict__ w3,
    const int*   __restrict__ pad_hv,       // (C_IN, 8)
    const int*   __restrict__ idx_identit,  // (C_OUT, 4)
    float* __restrict__ out)                // [out_h | out_v | out_i]
{
    const int co  = blockIdx.x;
    const int b   = blockIdx.y;
    const int tid = threadIdx.x;
    const int wv  = tid >> 6;
    const int w   = tid & 63;

    __shared__ __align__(16) float tile[TILE_DW];

    // One-time zero clear (row pads stay zero; interior rows overwritten per k)
    {
        const fvec4 z4 = {0.f, 0.f, 0.f, 0.f};
#pragma unroll
        for (int t = 0; t < 4; ++t) {
            int j = tid + t * 512;
            if (j < TILE_DW / 4) ((fvec4*)tile)[j] = z4;
        }
    }

    // Block-uniform identity-gather info
    int   kI[GRP];
    float w3v[GRP];
#pragma unroll
    for (int g = 0; g < GRP; ++g) {
        kI[g]  = idx_identit[co * GRP + g] - co * NK;
        w3v[g] = w3[g * C_OUT_N + co];
    }

    float accH[7], accV[7], accI[7];
#pragma unroll
    for (int i = 0; i < 7; ++i) { accH[i] = 0.f; accV[i] = 0.f; accI[i] = 0.f; }

    const float* chan_base = x + ((size_t)b * C_IN_N + (size_t)co * NK) * NELEM;

    // Prologue: prefetch channel k=0 (scalar dwords; idx-contiguous => coalesced)
    float pre[8];
#pragma unroll
    for (int t = 0; t < 8; ++t) {
        int idx = tid + t * 512;
        pre[t] = chan_base[idx < NELEM ? idx : NELEM - 1];
    }

    __syncthreads();   // clear done before first interior write

    const int h0   = wv * 7;
    const int colV = (w + EP < WIN) ? (w + EP) : (WIN - 1);   // clamp idle lanes
    const int baseVcol = colV * TSTR;
    const int rowB = h0 + EP + RPAD;                           // padded row of output row h0

#pragma unroll 1
    for (int k = 0; k < NK; ++k) {
        // regs -> LDS (row-major global -> column-major tile)
#pragma unroll
        for (int t = 0; t < 8; ++t) {
            int idx = tid + t * 512;
            if (idx < NELEM) {
                int row = idx / WIN;
                int col = idx - row * WIN;
                tile[col * TSTR + row + RPAD] = pre[t];
            }
        }
        __syncthreads();

        // Prefetch next channel while this one computes
        if (k < NK - 1) {
            const float* nxt = chan_base + (size_t)(k + 1) * NELEM;
#pragma unroll
            for (int t = 0; t < 8; ++t) {
                int idx = tid + t * 512;
                pre[t] = nxt[idx < NELEM ? idx : NELEM - 1];
            }
        }

        const int c = co * NK + k;
        // Block-uniform per-channel shifts & weights (scalar loads)
        int ph[GRP], pv[GRP];
        float a1[GRP], a2[GRP];
#pragma unroll
        for (int g = 0; g < GRP; ++g) {
            ph[g] = pad_hv[c * 8 + g];
            pv[g] = pad_hv[c * 8 + 4 + g];
            a1[g] = w1[g * C_IN_N + c];
            a2[g] = w2[g * C_IN_N + c];
        }
        float wi = 0.f;
#pragma unroll
        for (int g = 0; g < GRP; ++g)
            if (kI[g] == k) wi += w3v[g];

#pragma unroll
        for (int g = 0; g < GRP; ++g) {
            // H: column shift -> clamp col, zero the weight when OOB (per-lane)
            const int iw = w + EP + ph[g];
            const bool vH = (unsigned)iw < (unsigned)WIN;
            const int colH = vH ? iw : 0;
            const float a1m = vH ? a1[g] : 0.f;
            const int offH = colH * TSTR + rowB;                 // + i contiguous
            // V: row shift -> padded rows absorb OOB (always in-bounds, zeros)
            const int offV = baseVcol + rowB + pv[g];
#pragma unroll
            for (int i = 0; i < 7; ++i) {
                accH[i] = fmaf(tile[offH + i], a1m, accH[i]);
                accV[i] = fmaf(tile[offV + i], a2[g], accV[i]);
            }
        }
        if (wi != 0.f) {                 // block-uniform branch
            const int offI = baseVcol + rowB;
#pragma unroll
            for (int i = 0; i < 7; ++i)
                accI[i] = fmaf(tile[offI + i], wi, accI[i]);
        }
        __syncthreads();   // protect tile before next k's writes (and before epilogue)
    }

    // Epilogue: transpose through LDS -> full-line float4 nontemporal stores.
    // Barrier-fenced phases: no reliance on same-wave DS ordering or float/vec aliasing.
    const size_t OSZ  = (size_t)BATCH * C_OUT_N * HOUT * WOUT;
    const size_t rbase = (((size_t)b * C_OUT_N + co) * HOUT + h0) * WOUT;
    const int ebase = wv * (7 * WOUT);   // 392 dwords per wave (16B-aligned: 392%4==0)

    float* outs[3] = { out + rbase, out + OSZ + rbase, out + 2 * OSZ + rbase };
    const float* accs[3] = { accH, accV, accI };

#pragma unroll
    for (int o = 0; o < 3; ++o) {
        const float* a = accs[o];
        if (w < WOUT) {
#pragma unroll
            for (int i = 0; i < 7; ++i)
                tile[ebase + i * WOUT + w] = a[i];
        }
        __syncthreads();   // writes visible before reads
#pragma unroll
        for (int j = 0; j < 2; ++j) {
            int idx = w + j * 64;
            if (idx < 98) {
                const float* p = &tile[ebase + idx * 4];
                fvec4 v = { p[0], p[1], p[2], p[3] };   // type-consistent LDS reads
                __builtin_nontemporal_store(v, (fvec4*)(outs[o] + idx * 4));
            }
        }
        __syncthreads();   // reads done before next o's writes (WAR fence)
    }
}

extern "C" void kernel_launch(void* const* d_in, const int* in_sizes, int n_in,
                              void* d_out, int out_size, void* d_ws, size_t ws_size,
                              hipStream_t stream) {
    const float* x   = (const float*)d_in[0];
    const float* w1  = (const float*)d_in[1];
    const float* w2  = (const float*)d_in[2];
    const float* w3  = (const float*)d_in[3];
    const int* pad_hv      = (const int*)d_in[4];
    const int* idx_identit = (const int*)d_in[5];
    float* out = (float*)d_out;

    dim3 grid(C_OUT_N, BATCH);   // 768 blocks, 3 per CU x 8 waves = 24 waves/CU
    dim3 block(512);
    addshift_kernel<<<grid, block, 0, stream>>>(x, w1, w2, w3, pad_hv, idx_identit, out);
}